// Round 8
// baseline (319.948 us; speedup 1.0000x reference)
//
#include <hip/hip_runtime.h>
#include <hip/hip_bf16.h>
#include <stdint.h>

// Problem constants (AudioEncoder_14800457302115)
#define B_SZ    4
#define T_LEN   480000
#define S_LEN   240000          // (480000 + 2*2 - 5)/2 + 1
#define KS      5
#define PPB     7500            // 32-s tile-PAIRS per batch (240000/32)
#define NPAIRS  (B_SZ * PPB)    // 30000 wave-pairs
#define GRID    768             // 3 blocks/CU x 256 CU; 3072 waves

static_assert(4 * GRID <= PPB, "single-wrap batch advance requires nw <= PPB");

typedef __attribute__((ext_vector_type(8))) __bf16    bf16x8;
typedef __attribute__((ext_vector_type(4))) float     f32x4;
typedef __attribute__((ext_vector_type(2))) _Float16  f16x2;

// launch_bounds(256,3): min 3 waves/EU -> VGPR cap ~168. Natural usage with
// f16-packed conv weights is ~120-150, so NO spill (unlike (256,4) -> 64+spill).
__global__ __launch_bounds__(256, 3) void audio_enc_kernel(
    const float* __restrict__ audio,   // (B, T)
    const float* __restrict__ conv_w,  // (64, 1, 5)
    const float* __restrict__ conv_b,  // (64,)
    const float* __restrict__ lin_w,   // (64, 64) [p][e]
    const float* __restrict__ lin_b,   // (64,)
    float* __restrict__ out)           // (B, S, 64)
{
  const int lane = threadIdx.x & 63;
  const int m    = lane & 15;          // fragment free index (p for A, s for B)
  const int q    = lane >> 4;          // quad
  const int wid  = threadIdx.x >> 6;   // wave within block
  const int wv   = (int)((blockIdx.x << 2) | wid);
  const int nw   = (int)(gridDim.x << 2);

  // per-wave 8 KB staging (two 16-s tiles) for the store-layout transpose
  __shared__ float lds[4][2048];
  float* const lw = lds[wid];

  // ---- one-time, tile-invariant register state ----
  // conv weights packed f16 pairs (48 VGPR vs 80 fp32). x stays fp32;
  // only the weight is rounded (~5e-4 rel << bf16 MFMA error; R6-verified).
  f16x2 cwp[2][8][3];
  float cbv[2][8];
#pragma unroll
  for (int h = 0; h < 2; ++h)
#pragma unroll
    for (int j = 0; j < 8; ++j) {
      const int e = h * 32 + q * 8 + j;
      const float* w = conv_w + e * KS;
      cwp[h][j][0] = f16x2{(_Float16)w[0], (_Float16)w[1]};
      cwp[h][j][1] = f16x2{(_Float16)w[2], (_Float16)w[3]};
      cwp[h][j][2] = f16x2{(_Float16)w[4], (_Float16)0.f};
      cbv[h][j] = conv_b[e];
    }

  // lin_w as the MFMA *A* operand:
  // A[p][e]; lane: row = m -> p = nt*16+m, k = q*8+j -> e = kt*32+q*8+j
  bf16x8 wfrag[2][4];
#pragma unroll
  for (int nt = 0; nt < 4; ++nt) {
    const int p = nt * 16 + m;
#pragma unroll
    for (int kt = 0; kt < 2; ++kt) {
      const float* src = lin_w + p * 64 + kt * 32 + q * 8;
#pragma unroll
      for (int j = 0; j < 8; ++j) wfrag[kt][nt][j] = (__bf16)src[j];
    }
  }

  // lin_b folded into accumulator init: acc[r] is output column p = nt*16+q*4+r
  f32x4 lb4[4];
#pragma unroll
  for (int nt = 0; nt < 4; ++nt)
    lb4[nt] = *reinterpret_cast<const f32x4*>(lin_b + nt * 16 + q * 4);

  if (wv >= NPAIRS) return;
  int b  = wv / PPB;                   // 0 with this grid; kept general
  int sp = wv - b * PPB;               // pair index within batch

  // ---- 16-s tile window loader (branchless edge clamp) ----
  auto load_tile = [&](int bb, int s0, float2& A, float2& Bv, float& C) {
    const float* base = audio + (size_t)bb * T_LEN;
    const int sl = s0 + m;
    const int gi = 2 * sl - 2;                    // window start (pad=2)
    A = *reinterpret_cast<const float2*>(base + (gi < 0 ? 0 : gi));
    if (gi < 0) { A.x = 0.f; A.y = 0.f; }         // only s==0, m==0
    Bv = *reinterpret_cast<const float2*>(base + 2 * sl);
    const int ci = 2 * sl + 2;
    const float cv = base[ci < T_LEN ? ci : T_LEN - 1];
    C = (ci < T_LEN) ? cv : 0.f;                  // only sl==239999
  };

  float2 fa0, fb0, fa1, fb1; float c0, c1;
  load_tile(b, sp * 32,      fa0, fb0, c0);
  load_tile(b, sp * 32 + 16, fa1, fb1, c1);

  while (true) {
    // consume current pair's windows into locals, then issue next pair's loads
    const float xs0[KS] = {fa0.x, fa0.y, fb0.x, fb0.y, c0};
    const float xs1[KS] = {fa1.x, fa1.y, fb1.x, fb1.y, c1};
    const int bc = b, s0 = sp * 32;

    // incremental pair advance (no per-iter division)
    int spn = sp + nw, bn = b;
    if (spn >= PPB) { spn -= PPB; ++bn; }
    const bool more = (bn < B_SZ);
    if (more) {                                    // in-flight during compute
      load_tile(bn, spn * 32,      fa0, fb0, c0);
      load_tile(bn, spn * 32 + 16, fa1, fb1, c1);
    }

    // ---- conv -> feature fragments for BOTH tiles (weights amortized) ----
    // B[k=e][n=s]; lane: n = m, k = q*8+j -> e = h*32+q*8+j
    bf16x8 xf0[2], xf1[2];
#pragma unroll
    for (int h = 0; h < 2; ++h)
#pragma unroll
      for (int j = 0; j < 8; ++j) {
        const float w0 = (float)cwp[h][j][0][0];
        const float w1 = (float)cwp[h][j][0][1];
        const float w2 = (float)cwp[h][j][1][0];
        const float w3 = (float)cwp[h][j][1][1];
        const float w4 = (float)cwp[h][j][2][0];
        float a0 = cbv[h][j], a1 = cbv[h][j];
        a0 = fmaf(w0, xs0[0], a0);  a1 = fmaf(w0, xs1[0], a1);
        a0 = fmaf(w1, xs0[1], a0);  a1 = fmaf(w1, xs1[1], a1);
        a0 = fmaf(w2, xs0[2], a0);  a1 = fmaf(w2, xs1[2], a1);
        a0 = fmaf(w3, xs0[3], a0);  a1 = fmaf(w3, xs1[3], a1);
        a0 = fmaf(w4, xs0[4], a0);  a1 = fmaf(w4, xs1[4], a1);
        xf0[h][j] = (__bf16)fmaxf(a0, 0.f);
        xf1[h][j] = (__bf16)fmaxf(a1, 0.f);
      }

    // ---- MFMA both tiles; stage to LDS (XOR-swizzled, conflict-free) ----
    // D layout: row(p-in-chunk) = q*4+r, col(s) = m
    // tile u words [u*1024, u*1024+1024): word = m*64 + ((nt*16+q*4) ^ (m<<2))
#pragma unroll
    for (int nt = 0; nt < 4; ++nt) {
      f32x4 acc0 = lb4[nt];
      acc0 = __builtin_amdgcn_mfma_f32_16x16x32_bf16(wfrag[0][nt], xf0[0], acc0, 0, 0, 0);
      acc0 = __builtin_amdgcn_mfma_f32_16x16x32_bf16(wfrag[1][nt], xf0[1], acc0, 0, 0, 0);
      *reinterpret_cast<f32x4*>(lw + m * 64 + ((nt * 16 + q * 4) ^ (m << 2))) = acc0;
      f32x4 acc1 = lb4[nt];
      acc1 = __builtin_amdgcn_mfma_f32_16x16x32_bf16(wfrag[0][nt], xf1[0], acc1, 0, 0, 0);
      acc1 = __builtin_amdgcn_mfma_f32_16x16x32_bf16(wfrag[1][nt], xf1[1], acc1, 0, 0, 0);
      *reinterpret_cast<f32x4*>(lw + 1024 + m * 64 + ((nt * 16 + q * 4) ^ (m << 2))) = acc1;
    }

    // ---- read back in store order; 8 x 1024 B stores = 8 KB CONTIGUOUS ----
    // read lane l, instr g: tile u = g>>2, r = (g&3)*4 + (l>>4),
    //   word = u*1024 + r*64 + (((l&15)<<2) ^ (r<<2))
    float* ob = out + ((size_t)bc * S_LEN + (size_t)s0) * 64;
#pragma unroll
    for (int g = 0; g < 8; ++g) {
      const int r = (g & 3) * 4 + q;
      const f32x4 v = *reinterpret_cast<const f32x4*>(
          lw + (g >> 2) * 1024 + r * 64 + ((m << 2) ^ (r << 2)));
      *reinterpret_cast<f32x4*>(ob + g * 256 + lane * 4) = v;
    }

    if (!more) break;
    b = bn; sp = spn;
  }
}

extern "C" void kernel_launch(void* const* d_in, const int* in_sizes, int n_in,
                              void* d_out, int out_size, void* d_ws, size_t ws_size,
                              hipStream_t stream) {
  const float* audio  = (const float*)d_in[0];
  const float* conv_w = (const float*)d_in[1];
  const float* conv_b = (const float*)d_in[2];
  const float* lin_w  = (const float*)d_in[3];
  const float* lin_b  = (const float*)d_in[4];
  float* out = (float*)d_out;

  audio_enc_kernel<<<dim3(GRID), dim3(256), 0, stream>>>(
      audio, conv_w, conv_b, lin_w, lin_b, out);
}

// Round 11
// 256.820 us; speedup vs baseline: 1.2458x; 1.2458x over previous
//
#include <hip/hip_runtime.h>
#include <hip/hip_bf16.h>
#include <stdint.h>

// Problem constants (AudioEncoder_14800457302115)
// R11 = R7 (best, 261.8 us) + audio prefetch depth 2 (single variable).
#define B_SZ    4
#define T_LEN   480000
#define S_LEN   240000          // (480000 + 2*2 - 5)/2 + 1
#define KS      5
#define PPB     7500            // 32-s tile-PAIRS per batch (240000/32)
#define NPAIRS  (B_SZ * PPB)    // 30000 wave-pairs
#define GRID    512             // 2048 waves, 2 blk/CU resident (proven best)

static_assert(4 * GRID <= PPB, "single-wrap batch advance requires nw <= PPB");

typedef __attribute__((ext_vector_type(8))) __bf16  bf16x8;
typedef __attribute__((ext_vector_type(4))) float   f32x4;

__global__ __launch_bounds__(256) void audio_enc_kernel(
    const float* __restrict__ audio,   // (B, T)
    const float* __restrict__ conv_w,  // (64, 1, 5)
    const float* __restrict__ conv_b,  // (64,)
    const float* __restrict__ lin_w,   // (64, 64) [p][e]
    const float* __restrict__ lin_b,   // (64,)
    float* __restrict__ out)           // (B, S, 64)
{
  const int lane = threadIdx.x & 63;
  const int m    = lane & 15;          // fragment free index (p for A, s for B)
  const int q    = lane >> 4;          // quad
  const int wid  = threadIdx.x >> 6;   // wave within block
  const int wv   = (int)((blockIdx.x << 2) | wid);
  const int nw   = (int)(gridDim.x << 2);

  // per-wave 8 KB staging (two 16-s tiles) for the store-layout transpose
  __shared__ float lds[4][2048];
  float* const lw = lds[wid];

  // ---- one-time, tile-invariant register state (R7-proven fp32 weights) ----
  float cw[2][8][KS], cbv[2][8];
#pragma unroll
  for (int h = 0; h < 2; ++h)
#pragma unroll
    for (int j = 0; j < 8; ++j) {
      const int e = h * 32 + q * 8 + j;
#pragma unroll
      for (int t = 0; t < KS; ++t) cw[h][j][t] = conv_w[e * KS + t];
      cbv[h][j] = conv_b[e];
    }

  // lin_w as the MFMA *A* operand:
  // A[p][e]; lane: row = m -> p = nt*16+m, k = q*8+j -> e = kt*32+q*8+j
  bf16x8 wfrag[2][4];
#pragma unroll
  for (int nt = 0; nt < 4; ++nt) {
    const int p = nt * 16 + m;
#pragma unroll
    for (int kt = 0; kt < 2; ++kt) {
      const float* src = lin_w + p * 64 + kt * 32 + q * 8;
#pragma unroll
      for (int j = 0; j < 8; ++j) wfrag[kt][nt][j] = (__bf16)src[j];
    }
  }

  // lin_b folded into accumulator init: acc[r] is output column p = nt*16+q*4+r
  f32x4 lb4[4];
#pragma unroll
  for (int nt = 0; nt < 4; ++nt)
    lb4[nt] = *reinterpret_cast<const f32x4*>(lin_b + nt * 16 + q * 4);

  if (wv >= NPAIRS) return;
  int b0 = wv / PPB;                   // current pair id (b0, sp0)
  int sp0 = wv - b0 * PPB;
  int sp1 = sp0 + nw, b1 = b0;         // next pair id
  if (sp1 >= PPB) { sp1 -= PPB; ++b1; }
  bool v1 = (b1 < B_SZ);

  // ---- 16-s tile window loader (branchless edge clamp) ----
  auto load_tile = [&](int bb, int s0, float2& A, float2& Bv, float& C) {
    const float* base = audio + (size_t)bb * T_LEN;
    const int sl = s0 + m;
    const int gi = 2 * sl - 2;                    // window start (pad=2)
    A = *reinterpret_cast<const float2*>(base + (gi < 0 ? 0 : gi));
    if (gi < 0) { A.x = 0.f; A.y = 0.f; }         // only s==0, m==0
    Bv = *reinterpret_cast<const float2*>(base + 2 * sl);
    const int ci = 2 * sl + 2;
    const float cv = base[ci < T_LEN ? ci : T_LEN - 1];
    C = (ci < T_LEN) ? cv : 0.f;                  // only sl==239999
  };

  // ---- compute + store for one pair (R7 body, unchanged) ----
  auto body = [&](const float* xs0, const float* xs1, int bc, int s0c) {
    // conv -> feature fragments for both tiles (weights amortized)
    bf16x8 xf0[2], xf1[2];
#pragma unroll
    for (int h = 0; h < 2; ++h)
#pragma unroll
      for (int j = 0; j < 8; ++j) {
        float a0 = cbv[h][j], a1 = cbv[h][j];
#pragma unroll
        for (int t = 0; t < KS; ++t) {
          a0 = fmaf(cw[h][j][t], xs0[t], a0);
          a1 = fmaf(cw[h][j][t], xs1[t], a1);
        }
        xf0[h][j] = (__bf16)fmaxf(a0, 0.f);
        xf1[h][j] = (__bf16)fmaxf(a1, 0.f);
      }

    // MFMA both tiles; stage to LDS (XOR-swizzled, conflict-free)
    // D layout: row(p-in-chunk) = q*4+r, col(s) = m
#pragma unroll
    for (int nt = 0; nt < 4; ++nt) {
      f32x4 acc0 = lb4[nt];
      acc0 = __builtin_amdgcn_mfma_f32_16x16x32_bf16(wfrag[0][nt], xf0[0], acc0, 0, 0, 0);
      acc0 = __builtin_amdgcn_mfma_f32_16x16x32_bf16(wfrag[1][nt], xf0[1], acc0, 0, 0, 0);
      *reinterpret_cast<f32x4*>(lw + m * 64 + ((nt * 16 + q * 4) ^ (m << 2))) = acc0;
      f32x4 acc1 = lb4[nt];
      acc1 = __builtin_amdgcn_mfma_f32_16x16x32_bf16(wfrag[0][nt], xf1[0], acc1, 0, 0, 0);
      acc1 = __builtin_amdgcn_mfma_f32_16x16x32_bf16(wfrag[1][nt], xf1[1], acc1, 0, 0, 0);
      *reinterpret_cast<f32x4*>(lw + 1024 + m * 64 + ((nt * 16 + q * 4) ^ (m << 2))) = acc1;
    }

    // read back in store order; 8 x 1024 B stores = 8 KB contiguous
    float* ob = out + ((size_t)bc * S_LEN + (size_t)s0c) * 64;
#pragma unroll
    for (int g = 0; g < 8; ++g) {
      const int r = (g & 3) * 4 + q;
      const f32x4 v = *reinterpret_cast<const f32x4*>(
          lw + (g >> 2) * 1024 + r * 64 + ((m << 2) ^ (r << 2)));
      *reinterpret_cast<f32x4*>(ob + g * 256 + lane * 4) = v;
    }
  };

  // ---- prefetch depth 2: two named pair-buffers, 2-phase ping-pong ----
  // (named variables, not arrays: runtime-indexed regs would spill, rule #20)
  float2 A0a, B0a, A0b, B0b; float C0a, C0b;   // buffer P0
  float2 A1a, B1a, A1b, B1b; float C1a, C1b;   // buffer P1

  load_tile(b0, sp0 * 32,      A0a, B0a, C0a);
  load_tile(b0, sp0 * 32 + 16, A0b, B0b, C0b);
  if (v1) {
    load_tile(b1, sp1 * 32,      A1a, B1a, C1a);
    load_tile(b1, sp1 * 32 + 16, A1b, B1b, C1b);
  }

  while (true) {
    // ---- phase A: current pair in P0, next in P1; prefetch (cur+2) -> P0 ----
    {
      const float xs0[KS] = {A0a.x, A0a.y, B0a.x, B0a.y, C0a};
      const float xs1[KS] = {A0b.x, A0b.y, B0b.x, B0b.y, C0b};
      int sp2 = sp1 + nw, b2 = b1;
      if (sp2 >= PPB) { sp2 -= PPB; ++b2; }
      const bool v2 = (b2 < B_SZ);
      if (v2) {                                  // in flight for 2 iterations
        load_tile(b2, sp2 * 32,      A0a, B0a, C0a);
        load_tile(b2, sp2 * 32 + 16, A0b, B0b, C0b);
      }
      body(xs0, xs1, b0, sp0 * 32);
      if (!v1) break;
      b0 = b1; sp0 = sp1; b1 = b2; sp1 = sp2; v1 = v2;
    }
    // ---- phase B: current pair in P1, next in P0; prefetch (cur+2) -> P1 ----
    {
      const float xs0[KS] = {A1a.x, A1a.y, B1a.x, B1a.y, C1a};
      const float xs1[KS] = {A1b.x, A1b.y, B1b.x, B1b.y, C1b};
      int sp2 = sp1 + nw, b2 = b1;
      if (sp2 >= PPB) { sp2 -= PPB; ++b2; }
      const bool v2 = (b2 < B_SZ);
      if (v2) {
        load_tile(b2, sp2 * 32,      A1a, B1a, C1a);
        load_tile(b2, sp2 * 32 + 16, A1b, B1b, C1b);
      }
      body(xs0, xs1, b0, sp0 * 32);
      if (!v1) break;
      b0 = b1; sp0 = sp1; b1 = b2; sp1 = sp2; v1 = v2;
    }
  }
}

extern "C" void kernel_launch(void* const* d_in, const int* in_sizes, int n_in,
                              void* d_out, int out_size, void* d_ws, size_t ws_size,
                              hipStream_t stream) {
  const float* audio  = (const float*)d_in[0];
  const float* conv_w = (const float*)d_in[1];
  const float* conv_b = (const float*)d_in[2];
  const float* lin_w  = (const float*)d_in[3];
  const float* lin_b  = (const float*)d_in[4];
  float* out = (float*)d_out;

  audio_enc_kernel<<<dim3(GRID), dim3(256), 0, stream>>>(
      audio, conv_w, conv_b, lin_w, lin_b, out);
}